// Round 1
// baseline (221.557 us; speedup 1.0000x reference)
//
#include <hip/hip_runtime.h>
#include <math.h>

// Problem constants (match reference setup_inputs)
constexpr int B = 16;
constexpr int N = 4096;
constexpr int D = 512;
constexpr int R = 64;
constexpr int K = 128;
constexpr int WAVES = 8;          // 512-thread blocks for the accumulate pass
constexpr int KPW = K / WAVES;    // 16 rows per wave

// Scores staging buffer: s[b*N + n] = dot(x[b,n,:], W). 256 KiB, module-static
// (no hipMalloc allowed in kernel_launch; d_ws size is not guaranteed).
__device__ float g_scores[B * N];

// ---------------------------------------------------------------------------
// Pass 1: streaming GEMV — s[b,n] = x[b,n,:] . W  for ALL (b,n).
// Fully coalesced read of x (128 MiB), memory-bound. Butterfly reduce is fine
// here: it's hidden under HBM latency.
// grid = 2048 blocks x 256 threads; wave handles 8 consecutive rows.
// ---------------------------------------------------------------------------
__global__ __launch_bounds__(256, 8) void score_pass(
    const float* __restrict__ x,     // [B, N, D]
    const float* __restrict__ W)     // [D]
{
    const int tid  = threadIdx.x;
    const int lane = tid & 63;
    const int wave = tid >> 6;       // 0..3

    const float4* W4 = (const float4*)W;
    const float4  w0 = W4[lane];
    const float4  w1 = W4[lane + 64];

    const size_t gw   = (size_t)blockIdx.x * 4 + wave;   // 0..8191
    const size_t row0 = gw * 8;                          // covers B*N = 65536
    const float4* xr  = (const float4*)(x + row0 * D);   // 128 float4 per row

    // depth-1 prefetch
    float4 a0 = xr[lane];
    float4 a1 = xr[lane + 64];

    #pragma unroll
    for (int i = 0; i < 8; ++i) {
        float4 u0 = a0, u1 = a1;
        if (i + 1 < 8) {
            a0 = xr[(size_t)(i + 1) * 128 + lane];
            a1 = xr[(size_t)(i + 1) * 128 + lane + 64];
        }
        float p = u0.x * w0.x + u0.y * w0.y + u0.z * w0.z + u0.w * w0.w
                + u1.x * w1.x + u1.y * w1.y + u1.z * w1.z + u1.w * w1.w;
        #pragma unroll
        for (int off = 1; off < 64; off <<= 1)
            p += __shfl_xor(p, off, 64);
        if (lane == 0) g_scores[row0 + i] = p;
    }
}

// ---------------------------------------------------------------------------
// Pass 2: per-(b,r) softmax (once, over 128 precomputed scores) + weighted
// gather-accumulate. The hot loop has NO loop-carried serial work: just
// 2 float4 loads + 8 FMAs per row, depth-2 row prefetch.
// Bias b[0] is uniform across scores -> cancels in softmax; omitted.
// ---------------------------------------------------------------------------
__global__ __launch_bounds__(512, 8) void accum_pass(
    const float* __restrict__ x,     // [B, N, D]
    const int*   __restrict__ idx,   // [R, K]
    float* __restrict__ out)         // [B, R, D]
{
    // XCD swizzle: XCD j gets b in {2j, 2j+1} -> per-XCD unique working set
    // ~16 MiB; all row reuse (same b, different r) stays within one XCD.
    const int v    = blockIdx.x;          // 0..1023
    const int xcd  = v & 7;
    const int slot = v >> 3;              // 0..127
    const int b    = xcd * 2 + (slot >> 6);
    const int r    = slot & 63;

    const int tid  = threadIdx.x;
    const int lane = tid & 63;
    const int wave = tid >> 6;            // 0..7

    __shared__ int   s_idx[K];
    __shared__ float s_sc[K];
    __shared__ float s_at[K];
    __shared__ float s_O[WAVES][D];       // 16 KB partial outputs

    if (tid < K) s_idx[tid] = idx[r * K + tid];
    __syncthreads();

    // Issue the first two row loads NOW (they only depend on s_idx) so their
    // ~600-cycle latency hides under the score gather + softmax phase.
    const float* xb  = x + (size_t)b * N * D;
    const int kbase  = wave * KPW;
    const float4* rp0 = (const float4*)(xb + (size_t)s_idx[kbase] * D);
    float4 a0 = rp0[lane], a1 = rp0[lane + 64];
    const float4* rp1 = (const float4*)(xb + (size_t)s_idx[kbase + 1] * D);
    float4 c0 = rp1[lane], c1 = rp1[lane + 64];

    if (tid < K) s_sc[tid] = g_scores[b * N + s_idx[tid]];
    __syncthreads();

    // Softmax over 128 scores, computed once by wave 0 (2 scores/lane).
    if (wave == 0) {
        float p0 = s_sc[lane], p1 = s_sc[lane + 64];
        float m = fmaxf(p0, p1);
        #pragma unroll
        for (int off = 1; off < 64; off <<= 1)
            m = fmaxf(m, __shfl_xor(m, off, 64));
        float e0 = __expf(p0 - m);
        float e1 = __expf(p1 - m);
        float s = e0 + e1;
        #pragma unroll
        for (int off = 1; off < 64; off <<= 1)
            s += __shfl_xor(s, off, 64);
        const float inv = 1.0f / s;
        s_at[lane]      = e0 * inv;
        s_at[lane + 64] = e1 * inv;
    }
    __syncthreads();

    // Dependence-free weighted accumulate: 16 rows/wave, depth-2 prefetch.
    float4 O0 = make_float4(0.f, 0.f, 0.f, 0.f);
    float4 O1 = make_float4(0.f, 0.f, 0.f, 0.f);

    #pragma unroll
    for (int kk = 0; kk < KPW; ++kk) {
        const float wt = s_at[kbase + kk];    // wave-uniform LDS broadcast
        float4 u0 = a0, u1 = a1;
        a0 = c0; a1 = c1;
        if (kk + 2 < KPW) {
            const float4* rn = (const float4*)(xb + (size_t)s_idx[kbase + kk + 2] * D);
            c0 = rn[lane]; c1 = rn[lane + 64];
        }
        O0.x += wt * u0.x; O0.y += wt * u0.y; O0.z += wt * u0.z; O0.w += wt * u0.w;
        O1.x += wt * u1.x; O1.y += wt * u1.y; O1.z += wt * u1.z; O1.w += wt * u1.w;
    }

    // Stash per-wave partials (already softmax-normalized) and sum.
    ((float4*)&s_O[wave][0])[lane]      = O0;
    ((float4*)&s_O[wave][0])[lane + 64] = O1;
    __syncthreads();

    const int d = tid;                    // each thread owns one output dim
    float o = 0.0f;
    #pragma unroll
    for (int w = 0; w < WAVES; ++w) o += s_O[w][d];
    out[((size_t)b * R + r) * D + d] = o;
}

extern "C" void kernel_launch(void* const* d_in, const int* in_sizes, int n_in,
                              void* d_out, int out_size, void* d_ws, size_t ws_size,
                              hipStream_t stream) {
    const float* x    = (const float*)d_in[0];  // [B,N,D] fp32
    const int*   idx  = (const int*)d_in[1];    // [R,K] int32
    const float* W    = (const float*)d_in[2];  // [1,D] fp32
    // d_in[3] = bias, cancels in softmax
    float* out = (float*)d_out;                 // [B,R,D] fp32

    // Pass 1: 65536 rows / (4 waves * 8 rows) = 2048 blocks
    score_pass<<<dim3(2048), dim3(256), 0, stream>>>(x, W);
    // Pass 2: one block per (b, r)
    accum_pass<<<dim3(B * R), dim3(512), 0, stream>>>(x, idx, out);
}